// Round 1
// 547.528 us; speedup vs baseline: 1.4625x; 1.4625x over previous
//
#include <hip/hip_runtime.h>

typedef float f32x4 __attribute__((ext_vector_type(4)));
typedef short bf16x8 __attribute__((ext_vector_type(8)));
typedef unsigned short u16;

#define NEG_INF (-1e30f)

__device__ __forceinline__ u16 f2bf(float f) {
    unsigned u = __builtin_bit_cast(unsigned, f);
    unsigned r = u + 0x7FFFu + ((u >> 16) & 1u);  // RNE
    return (u16)(r >> 16);
}

__device__ __forceinline__ float wave_max(float v) {
    #pragma unroll
    for (int o = 32; o > 0; o >>= 1) v = fmaxf(v, __shfl_xor(v, o, 64));
    return v;
}
__device__ __forceinline__ float wave_sum(float v) {
    #pragma unroll
    for (int o = 32; o > 0; o >>= 1) v += __shfl_xor(v, o, 64);
    return v;
}
__device__ __forceinline__ void wave_argmax(float& v, int& i) {
    #pragma unroll
    for (int o = 32; o > 0; o >>= 1) {
        float ov = __shfl_xor(v, o, 64);
        int oi = __shfl_xor(i, o, 64);
        if (ov > v || (ov == v && oi < i)) { v = ov; i = oi; }
    }
}

// ---------------- staging ----------------
// Async global->LDS 16B (dwordx4). LDS dest must be wave-uniform base + lane*16:
// e = r*2048 + tid*8 gives per-wave byte base r*4096 + wave*1024, lane offset lane*16. OK.
__device__ __forceinline__ void g2l16(const void* g, void* l) {
    __builtin_amdgcn_global_load_lds((__attribute__((address_space(1))) void*)g,
                                     (__attribute__((address_space(3))) void*)l,
                                     16, 0, 0);
}

// Stage ROWSx64 bf16 tile (row-major, leading dim ld) into linear LDS [ROWS][64].
// NROUND = ROWS/32 (256 threads x 8 bf16 = 2048 elems = 32 rows per round).
template<int NROUND>
__device__ __forceinline__ void stage_bf16(const u16* __restrict__ src, int ld,
                                           u16* dst, int tid) {
    #pragma unroll
    for (int r = 0; r < NROUND; ++r) {
        int e = r * 2048 + tid * 8;
        int row = e >> 6, col = e & 63;
        g2l16(src + (size_t)row * ld + col, dst + e);
    }
}

// Stage 128x64 fp32 tile -> bf16 LDS (RNE in flight), via registers.
__device__ __forceinline__ void stage_f32_128(const float* __restrict__ src, int ld,
                                              u16* dst, int tid) {
    #pragma unroll
    for (int r = 0; r < 4; ++r) {
        int e = r * 2048 + tid * 8;
        int row = e >> 6, col = e & 63;
        const float* s = src + (size_t)row * ld + col;
        float4 a = *reinterpret_cast<const float4*>(s);
        float4 b = *reinterpret_cast<const float4*>(s + 4);
        uint4 pk;
        pk.x = (unsigned)f2bf(a.x) | ((unsigned)f2bf(a.y) << 16);
        pk.y = (unsigned)f2bf(a.z) | ((unsigned)f2bf(a.w) << 16);
        pk.z = (unsigned)f2bf(b.x) | ((unsigned)f2bf(b.y) << 16);
        pk.w = (unsigned)f2bf(b.z) | ((unsigned)f2bf(b.w) << 16);
        *reinterpret_cast<uint4*>(dst + e) = pk;
    }
}

// A/B-frag for mfma_f32_16x16x32_bf16 from linear LDS [*][64]:
// lane holds [m|n = lane&15][k = ks*32 + (lane>>4)*8 .. +7]
__device__ __forceinline__ bf16x8 frag(const u16* lds, int row0, int ks, int lane) {
    return *reinterpret_cast<const bf16x8*>(
        lds + (row0 + (lane & 15)) * 64 + ks * 32 + (lane >> 4) * 8);
}

// ---------------- GEMMs: 128x64 tile, BK=64, 4 waves (2x2, wave tile 64x32) ----------------

// C[128*by .. ][64*bx ..] (+)= A[M x K] * B[N x K]^T.  A: bf16 (ABF) or fp32; B: bf16.
template<bool ABF, bool ADD>
__global__ __launch_bounds__(256, 2) void gemm_bt64(
    const float* __restrict__ Af, const u16* __restrict__ Ab, const u16* __restrict__ B,
    float* __restrict__ C, int K, int ldA, int ldB, int ldC) {
    __shared__ u16 As[8192];   // 128x64
    __shared__ u16 Bs[4096];   // 64x64
    int tid = threadIdx.x, lane = tid & 63, wave = tid >> 6;
    int rowBase = blockIdx.y * 128, colBase = blockIdx.x * 64;
    int wm = (wave >> 1) * 64, wn = (wave & 1) * 32;
    f32x4 acc[4][2] = {};
    for (int k0 = 0; k0 < K; k0 += 64) {
        if constexpr (ABF) stage_bf16<4>(Ab + (size_t)rowBase * ldA + k0, ldA, As, tid);
        else               stage_f32_128(Af + (size_t)rowBase * ldA + k0, ldA, As, tid);
        stage_bf16<2>(B + (size_t)colBase * ldB + k0, ldB, Bs, tid);
        __syncthreads();   // compiler emits vmcnt(0) drain: global_load_lds complete
        #pragma unroll
        for (int ks = 0; ks < 2; ++ks) {
            bf16x8 af[4], bfr[2];
            #pragma unroll
            for (int i = 0; i < 4; ++i) af[i] = frag(As, wm + i * 16, ks, lane);
            #pragma unroll
            for (int j = 0; j < 2; ++j) bfr[j] = frag(Bs, wn + j * 16, ks, lane);
            #pragma unroll
            for (int i = 0; i < 4; ++i)
                #pragma unroll
                for (int j = 0; j < 2; ++j)
                    acc[i][j] = __builtin_amdgcn_mfma_f32_16x16x32_bf16(af[i], bfr[j], acc[i][j], 0, 0, 0);
        }
        __syncthreads();
    }
    // C/D layout (verified): col = lane&15, row = (lane>>4)*4 + reg
    int rq = (lane >> 4) * 4, cq = lane & 15;
    #pragma unroll
    for (int i = 0; i < 4; ++i)
        #pragma unroll
        for (int j = 0; j < 2; ++j) {
            int col = colBase + wn + j * 16 + cq;
            #pragma unroll
            for (int r = 0; r < 4; ++r) {
                int row = rowBase + wm + i * 16 + rq + r;
                size_t o = (size_t)row * ldC + col;
                if constexpr (ADD) C[o] = acc[i][j][r] + C[o];  // same-thread RMW
                else               C[o] = acc[i][j][r];
            }
        }
}

// Fused gate/up quarter: H2[:, 64*bx ..] = silu(x*Gq^T) * (x*Uq^T), bf16 out. K=1024.
template<bool ABF>
__global__ __launch_bounds__(256, 2) void gemm_gateup(
    const float* __restrict__ Af, const u16* __restrict__ Ab,
    const u16* __restrict__ G, const u16* __restrict__ U,
    u16* __restrict__ H2, int ldH) {
    __shared__ u16 As[8192];
    __shared__ u16 Gs[4096];
    __shared__ u16 Us[4096];
    int tid = threadIdx.x, lane = tid & 63, wave = tid >> 6;
    int rowBase = blockIdx.y * 128, colBase = blockIdx.x * 64;
    int wm = (wave >> 1) * 64, wn = (wave & 1) * 32;
    f32x4 ag[4][2] = {}, au[4][2] = {};
    for (int k0 = 0; k0 < 1024; k0 += 64) {
        if constexpr (ABF) stage_bf16<4>(Ab + (size_t)rowBase * 1024 + k0, 1024, As, tid);
        else               stage_f32_128(Af + (size_t)rowBase * 1024 + k0, 1024, As, tid);
        stage_bf16<2>(G + (size_t)colBase * 1024 + k0, 1024, Gs, tid);
        stage_bf16<2>(U + (size_t)colBase * 1024 + k0, 1024, Us, tid);
        __syncthreads();
        #pragma unroll
        for (int ks = 0; ks < 2; ++ks) {
            bf16x8 af[4], gf[2], uf[2];
            #pragma unroll
            for (int i = 0; i < 4; ++i) af[i] = frag(As, wm + i * 16, ks, lane);
            #pragma unroll
            for (int j = 0; j < 2; ++j) { gf[j] = frag(Gs, wn + j * 16, ks, lane);
                                          uf[j] = frag(Us, wn + j * 16, ks, lane); }
            #pragma unroll
            for (int i = 0; i < 4; ++i)
                #pragma unroll
                for (int j = 0; j < 2; ++j) {
                    ag[i][j] = __builtin_amdgcn_mfma_f32_16x16x32_bf16(af[i], gf[j], ag[i][j], 0, 0, 0);
                    au[i][j] = __builtin_amdgcn_mfma_f32_16x16x32_bf16(af[i], uf[j], au[i][j], 0, 0, 0);
                }
        }
        __syncthreads();
    }
    int rq = (lane >> 4) * 4, cq = lane & 15;
    #pragma unroll
    for (int i = 0; i < 4; ++i)
        #pragma unroll
        for (int j = 0; j < 2; ++j) {
            int col = colBase + wn + j * 16 + cq;
            #pragma unroll
            for (int r = 0; r < 4; ++r) {
                int row = rowBase + wm + i * 16 + rq + r;
                float g = ag[i][j][r], u = au[i][j][r];
                float h = (g / (1.f + __expf(-g))) * u;   // silu(g)*u
                H2[(size_t)row * ldH + col] = f2bf(h);
            }
        }
}

// ---------------- fp32 -> bf16 conversion (one-time, RNE identical to in-flight cast) ----
// i-th float4 group: row = i>>cl2, col = (i & ((1<<cl2)-1))*4 from src (leading dim srcLd);
// dst is packed row-major [rows][4<<cl2].
__global__ void conv_bf16(const float* __restrict__ s, u16* __restrict__ d,
                          int srcLd, int cl2, int total4) {
    int i = blockIdx.x * 256 + threadIdx.x;
    if (i >= total4) return;
    int r = i >> cl2, c = (i & ((1 << cl2) - 1)) * 4;
    float4 v = *reinterpret_cast<const float4*>(s + (size_t)r * srcLd + c);
    ushort4 pk;
    pk.x = f2bf(v.x); pk.y = f2bf(v.y); pk.z = f2bf(v.z); pk.w = f2bf(v.w);
    *reinterpret_cast<ushort4*>(d + (size_t)i * 4) = pk;
}

// ---------------- router / experts (unchanged, proven) ----------------
__global__ void bn_stats(const float* __restrict__ R, float* __restrict__ stats) {
    int c = threadIdx.x;
    int r0 = blockIdx.x * 64;
    float s = 0.f, s2 = 0.f;
    for (int r = r0; r < r0 + 64; ++r) {
        float v = R[(size_t)r * 256 + c];
        s += v; s2 += v * v;
    }
    atomicAdd(&stats[c], s);
    atomicAdd(&stats[256 + c], s2);
}

__global__ __launch_bounds__(64) void router_topk(
    const float* __restrict__ R, const float* __restrict__ stats,
    int* __restrict__ idx_out, float* __restrict__ wt_out) {
    int n = blockIdx.x, lane = threadIdx.x;
    const float invN = 1.0f / 4096.0f;
    float z[4];
    #pragma unroll
    for (int p = 0; p < 4; ++p) {
        int c = p * 64 + lane;
        float mean = stats[c] * invN;
        float var = fmaxf(stats[256 + c] * invN - mean * mean, 0.f);
        float v = R[(size_t)n * 256 + c];
        z[p] = (v - mean) * rsqrtf(var + 1e-5f);
    }
    float mx = wave_max(fmaxf(z[0], z[1]));
    float sx = __logf(wave_sum(__expf(z[0] - mx) + __expf(z[1] - mx)));
    float lx0 = z[0] - mx - sx, lx1 = z[1] - mx - sx;
    float my = wave_max(fmaxf(z[2], z[3]));
    float sy = __logf(wave_sum(__expf(z[2] - my) + __expf(z[3] - my)));
    float ly0 = z[2] - my - sy, ly1 = z[3] - my - sy;

    __shared__ float tx[16], ty[16];
    __shared__ int txc[16], tyc[16];
    float v0 = lx0, v1 = lx1;
    for (int t = 0; t < 16; ++t) {
        float bv; int bc;
        if (v1 > v0) { bv = v1; bc = lane + 64; } else { bv = v0; bc = lane; }
        wave_argmax(bv, bc);
        if (lane == 0) { tx[t] = bv; txc[t] = bc; }
        if (bc == lane) v0 = NEG_INF;
        else if (bc == lane + 64) v1 = NEG_INF;
    }
    v0 = ly0; v1 = ly1;
    for (int t = 0; t < 16; ++t) {
        float bv; int bc;
        if (v1 > v0) { bv = v1; bc = lane + 64; } else { bv = v0; bc = lane; }
        wave_argmax(bv, bc);
        if (lane == 0) { ty[t] = bv; tyc[t] = bc; }
        if (bc == lane) v0 = NEG_INF;
        else if (bc == lane + 64) v1 = NEG_INF;
    }
    __syncthreads();
    float cv[4]; int ci[4];
    #pragma unroll
    for (int p = 0; p < 4; ++p) {
        int pid = p * 64 + lane;
        cv[p] = tx[pid >> 4] + ty[pid & 15];
        ci[p] = pid;
    }
    for (int t = 0; t < 16; ++t) {
        float bv = cv[0]; int bc = ci[0];
        #pragma unroll
        for (int p = 1; p < 4; ++p)
            if (cv[p] > bv) { bv = cv[p]; bc = ci[p]; }
        wave_argmax(bv, bc);
        if (lane == 0) {
            idx_out[n * 16 + t] = txc[bc >> 4] * 128 + tyc[bc & 15];
            wt_out[n * 16 + t] = __expf(bv);
        }
        #pragma unroll
        for (int p = 0; p < 4; ++p)
            if (ci[p] == bc) cv[p] = NEG_INF;
    }
}

__global__ __launch_bounds__(256) void expert_store(
    const float* __restrict__ X, const float* __restrict__ UE, const float* __restrict__ DE,
    const int* __restrict__ idxs, const float* __restrict__ wts, float* __restrict__ Out) {
    int n = blockIdx.x, tid = threadIdx.x;
    int lane = tid & 63, wave = tid >> 6;
    __shared__ float xs[1024];
    __shared__ float ews[16];
    __shared__ int sidx[16];
    __shared__ float swt[16];
    if (tid < 16) {
        sidx[tid] = min(max(idxs[n * 16 + tid], 0), 16383);
        swt[tid] = wts[n * 16 + tid];
    }
    {
        float4 v = reinterpret_cast<const float4*>(X + (size_t)n * 1024)[tid];
        *reinterpret_cast<float4*>(xs + tid * 4) = v;
    }
    __syncthreads();
    #pragma unroll
    for (int q = 0; q < 4; ++q) {
        int e = wave * 4 + q;
        const float* row = UE + (size_t)sidx[e] * 1024;
        float acc = 0.f;
        #pragma unroll
        for (int c = 0; c < 4; ++c) {
            int h = c * 256 + lane * 4;
            float4 a = *reinterpret_cast<const float4*>(row + h);
            float4 xv = *reinterpret_cast<const float4*>(xs + h);
            acc += a.x * xv.x + a.y * xv.y + a.z * xv.z + a.w * xv.w;
        }
        acc = wave_sum(acc);
        if (lane == 0) {
            float s = acc / (1.f + __expf(-acc));
            ews[e] = s * swt[e];
        }
    }
    __syncthreads();
    float4 a = make_float4(0.f, 0.f, 0.f, 0.f);
    int h = tid * 4;
    #pragma unroll
    for (int e = 0; e < 16; ++e) {
        const float* row = DE + (size_t)sidx[e] * 1024;
        float4 v = *reinterpret_cast<const float4*>(row + h);
        float w = ews[e];
        a.x += w * v.x; a.y += w * v.y;
        a.z += w * v.z; a.w += w * v.w;
    }
    reinterpret_cast<float4*>(Out + (size_t)n * 1024)[tid] = a;
}

// ---------------- host ----------------
// Workspace (exact fit = 38,289,408 B, the floor proven by the previous chunk=4096 run):
//   stats 16KB | idx 256KB | wt 256KB | W 4MB (bf16 weight staging: router wts /
//   gw+uw quarter pair / dw K-half) | union32 32MB { R 4MB (router phase) -> H2 (dense) }
// If ws_size has 8MB spare, x is pre-converted to bf16 (xb) so GEMM A uses global_load_lds.
extern "C" void kernel_launch(void* const* d_in, const int* in_sizes, int n_in,
                              void* d_out, int out_size, void* d_ws, size_t ws_size,
                              hipStream_t stream) {
    const float* x   = (const float*)d_in[0];   // [4096,1024]
    const float* gw  = (const float*)d_in[1];   // [4096,1024]
    const float* uw  = (const float*)d_in[2];   // [4096,1024]
    const float* dw  = (const float*)d_in[3];   // [1024,4096]
    const float* rxw = (const float*)d_in[4];   // [128,1024]
    const float* ryw = (const float*)d_in[5];   // [128,1024]
    const float* ue  = (const float*)d_in[6];   // [16384,1024]
    const float* de  = (const float*)d_in[7];   // [16384,1024]
    float* out = (float*)d_out;                 // [4096,1024] fp32

    char* p = (char*)d_ws;
    float* stats = (float*)p; p += 16384;
    int*   idxb  = (int*)p;   p += 262144;
    float* wtb   = (float*)p; p += 262144;
    u16*   W     = (u16*)p;   p += 4194304;
    float* R     = (float*)p;                   // router scores [4096,256] (dead after topk)
    u16*   H2    = (u16*)p;                     // aliases R: [4096,4096] bf16 (dense phase)

    bool useXb = ws_size >= 38289408ull + 8388608ull;
    u16* xb = (u16*)((char*)d_ws + 38289408ull);

    hipMemsetAsync(stats, 0, 512 * sizeof(float), stream);

    // router weights -> W[0:256,1024] bf16 (rxw rows 0..127, ryw rows 128..255)
    conv_bf16<<<128, 256, 0, stream>>>(rxw, W, 1024, 8, 32768);
    conv_bf16<<<128, 256, 0, stream>>>(ryw, W + 131072, 1024, 8, 32768);
    if (useXb) conv_bf16<<<4096, 256, 0, stream>>>(x, xb, 1024, 8, 1048576);

    // R = x @ [rxw;ryw]^T : one launch, grid (4,32)=128 blocks
    if (useXb) gemm_bt64<true , false><<<dim3(4, 32), 256, 0, stream>>>(nullptr, xb, W, R, 1024, 1024, 1024, 256);
    else       gemm_bt64<false, false><<<dim3(4, 32), 256, 0, stream>>>(x, nullptr, W, R, 1024, 1024, 1024, 256);

    bn_stats<<<64, 256, 0, stream>>>(R, stats);
    router_topk<<<4096, 64, 0, stream>>>(R, stats, idxb, wtb);
    expert_store<<<4096, 256, 0, stream>>>(x, ue, de, idxb, wtb, out);   // experts -> out

    // dense gate/up in 4 column-quarters (W holds gwq 2MB + uwq 2MB); grid 512 = 2 blocks/CU
    for (int q = 0; q < 4; ++q) {
        conv_bf16<<<1024, 256, 0, stream>>>(gw + (size_t)q * 1048576, W, 1024, 8, 262144);
        conv_bf16<<<1024, 256, 0, stream>>>(uw + (size_t)q * 1048576, W + 1048576, 1024, 8, 262144);
        if (useXb) gemm_gateup<true ><<<dim3(16, 32), 256, 0, stream>>>(nullptr, xb, W, W + 1048576, H2 + q * 1024, 4096);
        else       gemm_gateup<false><<<dim3(16, 32), 256, 0, stream>>>(x, nullptr, W, W + 1048576, H2 + q * 1024, 4096);
    }
    // down in 2 K-halves (W holds dw[:, h*2048 .. +2048] bf16); out += partial each launch
    for (int h = 0; h < 2; ++h) {
        conv_bf16<<<2048, 256, 0, stream>>>(dw + h * 2048, W, 4096, 9, 524288);
        gemm_bt64<true, true><<<dim3(16, 32), 256, 0, stream>>>(nullptr, H2 + h * 2048, W, out, 2048, 4096, 2048, 1024);
    }
}